// Round 7
// baseline (4251.777 us; speedup 1.0000x reference)
//
#include <hip/hip_runtime.h>
#include <hip/hip_bf16.h>
#include <math.h>

#define BATCH   512
#define IN_DIM  4096
#define HID_DIM 8192
#define OUT_DIM 1024
#define T_STEPS 10
#define LEAK    0.95f

typedef __attribute__((ext_vector_type(8))) short bf16x8;
typedef __attribute__((ext_vector_type(8))) unsigned short ushort8;
typedef __attribute__((ext_vector_type(4))) float floatx4;

__device__ __forceinline__ unsigned short f2bf(float f) {
    unsigned int u = __float_as_uint(f);
    u += 0x7fffu + ((u >> 16) & 1u);   // RNE
    return (unsigned short)(u >> 16);
}

// ---------------------------------------------------------------------------
// r = bf16(sigmoid(x)), 4 elems/thread
// ---------------------------------------------------------------------------
__global__ __launch_bounds__(256) void rates_bf16(const float* __restrict__ x,
                                                  unsigned short* __restrict__ r, int n4) {
    int i = blockIdx.x * blockDim.x + threadIdx.x;
    if (i >= n4) return;
    float4 v = ((const float4*)x)[i];
    ushort4 o;
    o.x = f2bf(1.f / (1.f + __expf(-v.x)));
    o.y = f2bf(1.f / (1.f + __expf(-v.y)));
    o.z = f2bf(1.f / (1.f + __expf(-v.z)));
    o.w = f2bf(1.f / (1.f + __expf(-v.w)));
    ((ushort4*)r)[i] = o;
}

// ---------------------------------------------------------------------------
// transpose + convert: in fp32 [K][N] -> out bf16 [N][K]; 64x64 tiles.
// ---------------------------------------------------------------------------
__global__ __launch_bounds__(256) void transpose_cvt(const float* __restrict__ in,
                                                     unsigned short* __restrict__ out,
                                                     int K, int N) {
    __shared__ float tile[64][65];
    const int nb = blockIdx.x * 64;
    const int kb = blockIdx.y * 64;
    const int t = threadIdx.x;
    const int tr = t >> 4;
    const int tc4 = (t & 15) * 4;
#pragma unroll
    for (int it = 0; it < 4; ++it) {
        int k = tr + 16 * it;
        float4 v = *(const float4*)&in[(size_t)(kb + k) * N + nb + tc4];
        tile[k][tc4 + 0] = v.x;
        tile[k][tc4 + 1] = v.y;
        tile[k][tc4 + 2] = v.z;
        tile[k][tc4 + 3] = v.w;
    }
    __syncthreads();
    const int k8 = (t & 7) * 8;
    const int nr = t >> 3;          // 0..31
#pragma unroll
    for (int it = 0; it < 2; ++it) {
        int n = nr + 32 * it;
        ushort8 o;
#pragma unroll
        for (int j = 0; j < 8; ++j) o[j] = f2bf(tile[k8 + j][n]);
        *(ushort8*)&out[(size_t)(nb + n) * K + kb + k8] = o;
    }
}

// ---------------------------------------------------------------------------
// No-LDS direct-fragment MFMA GEMM: C[M,N] = A[M,K] @ Bt[N,K]^T.
// Both operands pre-laid-out so each lane's 16x16x32 fragment is 16B
// CONTIGUOUS in global: lane(fq=lane>>4, fr=lane&15) reads row (tile+fr),
// k = fq*8..fq*8+7 -> global_load_dwordx4 straight into the MFMA operand.
// No LDS, no barriers: compiler pipelines loads vs MFMA with vmcnt(N).
// 64x64 tile, 4 waves in 2x2 (32x32 each), K unrolled by 64 (8 loads+8 MFMA
// independent per iteration). Grid (N/64, M/64): blocks sharing a B-tile are
// 128 apart in linear id == same id%8 -> same XCD L2.
// ---------------------------------------------------------------------------
__global__ __launch_bounds__(256) void gemm_direct(const unsigned short* __restrict__ A,
                                                   const unsigned short* __restrict__ Bt,
                                                   float* __restrict__ C,
                                                   int M, int N, int K) {
    const int tid = threadIdx.x;
    const int wave = tid >> 6;
    const int lane = tid & 63;
    const int wr = wave >> 1;
    const int wc = wave & 1;
    const int fr = lane & 15;
    const int fq = lane >> 4;

    const int m0 = blockIdx.y * 64;
    const int n0 = blockIdx.x * 64;

    const unsigned short* ap0 = A + (size_t)(m0 + wr * 32 + fr) * K + fq * 8;
    const unsigned short* ap1 = ap0 + (size_t)16 * K;
    const unsigned short* bp0 = Bt + (size_t)(n0 + wc * 32 + fr) * K + fq * 8;
    const unsigned short* bp1 = bp0 + (size_t)16 * K;

    floatx4 acc[2][2] = {};

    for (int k0 = 0; k0 < K; k0 += 64) {
        bf16x8 a00 = *(const bf16x8*)(ap0 + k0);
        bf16x8 a10 = *(const bf16x8*)(ap1 + k0);
        bf16x8 b00 = *(const bf16x8*)(bp0 + k0);
        bf16x8 b10 = *(const bf16x8*)(bp1 + k0);
        bf16x8 a01 = *(const bf16x8*)(ap0 + k0 + 32);
        bf16x8 a11 = *(const bf16x8*)(ap1 + k0 + 32);
        bf16x8 b01 = *(const bf16x8*)(bp0 + k0 + 32);
        bf16x8 b11 = *(const bf16x8*)(bp1 + k0 + 32);
        acc[0][0] = __builtin_amdgcn_mfma_f32_16x16x32_bf16(a00, b00, acc[0][0], 0, 0, 0);
        acc[0][1] = __builtin_amdgcn_mfma_f32_16x16x32_bf16(a00, b10, acc[0][1], 0, 0, 0);
        acc[1][0] = __builtin_amdgcn_mfma_f32_16x16x32_bf16(a10, b00, acc[1][0], 0, 0, 0);
        acc[1][1] = __builtin_amdgcn_mfma_f32_16x16x32_bf16(a10, b10, acc[1][1], 0, 0, 0);
        acc[0][0] = __builtin_amdgcn_mfma_f32_16x16x32_bf16(a01, b01, acc[0][0], 0, 0, 0);
        acc[0][1] = __builtin_amdgcn_mfma_f32_16x16x32_bf16(a01, b11, acc[0][1], 0, 0, 0);
        acc[1][0] = __builtin_amdgcn_mfma_f32_16x16x32_bf16(a11, b01, acc[1][0], 0, 0, 0);
        acc[1][1] = __builtin_amdgcn_mfma_f32_16x16x32_bf16(a11, b11, acc[1][1], 0, 0, 0);
    }

#pragma unroll
    for (int i = 0; i < 2; ++i) {
#pragma unroll
        for (int j = 0; j < 2; ++j) {
            int row = m0 + wr * 32 + i * 16 + fq * 4;
            int col = n0 + wc * 32 + j * 16 + fr;
#pragma unroll
            for (int r = 0; r < 4; ++r)
                C[(size_t)(row + r) * N + col] = acc[i][j][r];
        }
    }
}

// ---------------------------------------------------------------------------
// First-spike scan (exact structural reduction: REFRACT=1 & t=spike_count =>
// each neuron spikes at most once ever; adaptation unreachable). Finds the
// batch index of the single spike (or -1). Wave-level early exit.
// ---------------------------------------------------------------------------
__global__ __launch_bounds__(256) void first_spike(const float* __restrict__ cur,
                                                   int* __restrict__ b_fire, int n) {
    int j = blockIdx.x * blockDim.x + threadIdx.x;
    float v = 0.f;
    bool fired = false;
    int bf = -1;
    for (int b = 0; b < BATCH; ++b) {
        float c = cur[(size_t)b * n + j];
#pragma unroll
        for (int t = 0; t < T_STEPS; ++t) {
            v = v * LEAK + c;
            if (!fired && v >= 1.0f) { fired = true; bf = b; }
        }
        if (__all((int)fired)) break;
    }
    b_fire[j] = bf;
}

// ---------------------------------------------------------------------------
// Bucket hidden neurons by firing batch: list[b][i] = j for each j with
// bfire[j]==b. cnt pre-zeroed via hipMemsetAsync.
// ---------------------------------------------------------------------------
__global__ __launch_bounds__(256) void bucket_kernel(const int* __restrict__ bfire,
                                                     int* __restrict__ cnt,
                                                     int* __restrict__ list) {
    int j = blockIdx.x * blockDim.x + threadIdx.x;
    int b = bfire[j];
    if (b >= 0) {
        int pos = atomicAdd(&cnt[b], 1);
        list[(size_t)b * HID_DIM + pos] = j;
    }
}

// ---------------------------------------------------------------------------
// Gather layer-2: cur_o[b][k] = 0.1 * sum_{j in list[b]} W_ho[j][k].
// Block b reads only its ~(HID/BATCH) rows; each row = 4KB, exactly one
// coalesced float4 load per thread.
// ---------------------------------------------------------------------------
__global__ __launch_bounds__(256) void gather_gemm(const int* __restrict__ cnt,
                                                   const int* __restrict__ list,
                                                   const float* __restrict__ W_ho,
                                                   float* __restrict__ cur_o) {
    const int b = blockIdx.x;
    const int n = cnt[b];
    const int k4 = threadIdx.x * 4;
    const int* lp = &list[(size_t)b * HID_DIM];
    float4 acc = make_float4(0.f, 0.f, 0.f, 0.f);
    for (int i = 0; i < n; ++i) {
        int j = lp[i];
        float4 w = *(const float4*)&W_ho[(size_t)j * OUT_DIM + k4];
        acc.x += w.x; acc.y += w.y; acc.z += w.z; acc.w += w.w;
    }
    acc.x *= 0.1f; acc.y *= 0.1f; acc.z *= 0.1f; acc.w *= 0.1f;
    *(float4*)&cur_o[(size_t)b * OUT_DIM + k4] = acc;
}

// out[b][k] = (b_fire[k]==b) ? 0.1f : 0, fp32, 4 elems/thread
__global__ __launch_bounds__(256) void write_out_f32(const int* __restrict__ b_fire,
                                                     float* __restrict__ out) {
    int gid = blockIdx.x * blockDim.x + threadIdx.x;       // over B*OUT/4
    int b = gid >> 8;                                      // OUT/4 = 256
    int k = (gid & 255) << 2;
    int4 bf = *(const int4*)&b_fire[k];
    float4 o;
    o.x = (bf.x == b) ? 0.1f : 0.f;
    o.y = (bf.y == b) ? 0.1f : 0.f;
    o.z = (bf.z == b) ? 0.1f : 0.f;
    o.w = (bf.w == b) ? 0.1f : 0.f;
    *(float4*)&out[(size_t)b * OUT_DIM + k] = o;
}

// ---------------------------------------------------------------------------
extern "C" void kernel_launch(void* const* d_in, const int* in_sizes, int n_in,
                              void* d_out, int out_size, void* d_ws, size_t ws_size,
                              hipStream_t stream) {
    const float* x    = (const float*)d_in[0];  // [512, 4096]
    const float* W_ih = (const float*)d_in[1];  // [4096, 8192]
    const float* W_ho = (const float*)d_in[2];  // [8192, 1024]
    float* out = (float*)d_out;                 // [512, 1024] fp32

    char* base = (char*)d_ws;
    float*          cur_h   = (float*)(base + 0);                  // 16.8 MB
    unsigned short* r_bf    = (unsigned short*)(base + 16777216);  //  4.2 MB
    int*            bfire_h = (int*)(base + 20971520);             //  32 KB
    int*            bfire_o = (int*)(base + 21004288);             //   4 KB
    int*            cnt     = (int*)(base + 21008384);             //   2 KB
    float*          cur_o   = (float*)(base + 22020096);           //   2 MB
    unsigned short* Wt      = (unsigned short*)(base + 31457280);  // 64 MB (ends ~95.5 MB)
    int*            list    = (int*)(base + 31457280);             // 16 MB, aliases Wt (used after)

    // 1) input rates -> bf16 [512][4096]
    int n4 = BATCH * IN_DIM / 4;
    rates_bf16<<<n4 / 256, 256, 0, stream>>>(x, r_bf, n4);

    // 2) Wt = bf16(W_ih^T)  [8192][4096]
    transpose_cvt<<<dim3(HID_DIM / 64, IN_DIM / 64), 256, 0, stream>>>(W_ih, Wt, IN_DIM, HID_DIM);

    // 3) cur_h = r_bf @ Wt^T  [512][8192]; barrier-free direct-fragment GEMM
    gemm_direct<<<dim3(HID_DIM / 64, BATCH / 64), 256, 0, stream>>>(
        r_bf, Wt, cur_h, BATCH, HID_DIM, IN_DIM);

    // 4) hidden first-spike scan -> bfire_h [8192]
    first_spike<<<HID_DIM / 256, 256, 0, stream>>>(cur_h, bfire_h, HID_DIM);

    // 5) bucket by firing batch (Wt consumed; list may alias it)
    hipMemsetAsync(cnt, 0, BATCH * sizeof(int), stream);
    bucket_kernel<<<HID_DIM / 256, 256, 0, stream>>>(bfire_h, cnt, list);

    // 6) gather layer 2: cur_o[b] = 0.1 * sum of this batch's W_ho rows
    gather_gemm<<<BATCH, 256, 0, stream>>>(cnt, list, W_ho, cur_o);

    // 7) output first-spike scan -> bfire_o [1024]
    first_spike<<<OUT_DIM / 256, 256, 0, stream>>>(cur_o, bfire_o, OUT_DIM);

    // 8) d_out [512][1024] fp32 (wide, coalesced)
    write_out_f32<<<(BATCH * OUT_DIM / 4) / 256, 256, 0, stream>>>(bfire_o, out);
}